// Round 1
// 54.733 us; speedup vs baseline: 1.0166x; 1.0166x over previous
//
#include <hip/hip_runtime.h>
#include <math.h>

// Problem constants (from setup_inputs): B=4, N=2048 (unused — cancels), M=8192.
#define ICA_M     8192
#define ICA_BLOCK 1024
#define ICA_VPT   (ICA_M / (ICA_BLOCK * 4))   // float4 vectors per thread = 2
#define ICA_WAVES (ICA_BLOCK / 64)            // 16 waves/block

// Algebraic reduction of the reference:
//   attn[b,i,j] = softmax_j(-(Q2_i + K2_j)) = softmax_j(-K2_j)   (row-shift invariance)
//   context[b,i] = sum_j softmax_j(-K2_j) * K2_j                  (independent of i)
//   out[b] = mean_i context[b,i] = sum_j exp(-K2_j)*K2_j / sum_j exp(-K2_j)
// where K2_j = (x_j - mean(x))^2, x = all_atom_features[b,:,0].
//
// Latency-tail tuning: 4 blocks only (one per batch), so per-CU TLP is all we
// have. block=1024 → 16 waves/CU (vs 4 at block=256), per-thread serial work
// cut 4× (2 float4 loads, 8 expf). Both block-reduces end in a wave-0 shuffle
// instead of a serial scalar loop.
__global__ __launch_bounds__(ICA_BLOCK) void
InvariantCrossAttention_39582418600293_kernel(const float* __restrict__ all_atom,
                                              float* __restrict__ out) {
    const int b    = blockIdx.x;
    const int tid  = threadIdx.x;
    const int wave = tid >> 6, lane = tid & 63;
    const float4* base = (const float4*)(all_atom + (size_t)b * ICA_M);

    // ---- pass 1 (registers): load 32 KB/block as float4, partial sum ----
    float4 v[ICA_VPT];
    float s = 0.f;
#pragma unroll
    for (int i = 0; i < ICA_VPT; ++i) {
        v[i] = base[tid + i * ICA_BLOCK];           // coalesced: lane-contiguous
        s += (v[i].x + v[i].y) + (v[i].z + v[i].w);
    }

    // block reduce s -> mean (wave shuffle, then wave-0 shuffle over partials)
    __shared__ float red[ICA_WAVES];
    __shared__ float s_mean;
#pragma unroll
    for (int off = 32; off > 0; off >>= 1) s += __shfl_down(s, off, 64);
    if (lane == 0) red[wave] = s;
    __syncthreads();
    if (wave == 0) {
        float t = (lane < ICA_WAVES) ? red[lane] : 0.f;
#pragma unroll
        for (int off = ICA_WAVES / 2; off > 0; off >>= 1) t += __shfl_down(t, off, 64);
        if (lane == 0) s_mean = t * (1.0f / (float)ICA_M);
    }
    __syncthreads();
    const float mean = s_mean;

    // ---- pass 2 (registers only): num/den of the softmax-weighted K2 ----
    float num = 0.f, den = 0.f;
#pragma unroll
    for (int i = 0; i < ICA_VPT; ++i) {
        float d0 = v[i].x - mean, d1 = v[i].y - mean,
              d2 = v[i].z - mean, d3 = v[i].w - mean;
        float k0 = d0 * d0, k1 = d1 * d1, k2 = d2 * d2, k3 = d3 * d3;
        float e0 = __expf(-k0), e1 = __expf(-k1),
              e2 = __expf(-k2), e3 = __expf(-k3);
        den += (e0 + e1) + (e2 + e3);
        num += (e0 * k0 + e1 * k1) + (e2 * k2 + e3 * k3);
    }

    // block reduce (num, den) together
#pragma unroll
    for (int off = 32; off > 0; off >>= 1) {
        num += __shfl_down(num, off, 64);
        den += __shfl_down(den, off, 64);
    }
    __shared__ float rnum[ICA_WAVES], rden[ICA_WAVES];
    if (lane == 0) { rnum[wave] = num; rden[wave] = den; }
    __syncthreads();
    if (wave == 0) {
        float tn = (lane < ICA_WAVES) ? rnum[lane] : 0.f;
        float td = (lane < ICA_WAVES) ? rden[lane] : 0.f;
#pragma unroll
        for (int off = ICA_WAVES / 2; off > 0; off >>= 1) {
            tn += __shfl_down(tn, off, 64);
            td += __shfl_down(td, off, 64);
        }
        if (lane == 0) out[b] = tn / td;
    }
}

extern "C" void kernel_launch(void* const* d_in, const int* in_sizes, int n_in,
                              void* d_out, int out_size, void* d_ws, size_t ws_size,
                              hipStream_t stream) {
    // d_in[0]: cdr3_features [4,2048,1] fp32 — mathematically unused (softmax
    //          row-shift invariance cancels the Q2 term).
    // d_in[1]: all_atom_features [4,8192,1] fp32.
    const float* all_atom = (const float*)d_in[1];
    float* out = (float*)d_out;                      // out_size == 4 (B=4)

    InvariantCrossAttention_39582418600293_kernel<<<4, ICA_BLOCK, 0, stream>>>(all_atom, out);
}